// Round 12
// baseline (40.950 us; speedup 1.0000x reference)
//
#include <hip/hip_runtime.h>
#include <cstdint>

#define B_ROWS 4096
#define N_ROWS 8192
#define D_DIM  256
#define BT     128                 // block tile 128x128
#define TGRID  64                  // 8192 / 128
#define NTILES 2080                // TGRID*(TGRID+1)/2

typedef __attribute__((ext_vector_type(4))) float f32x4;
typedef __attribute__((ext_vector_type(2))) unsigned long u64x2;

__device__ __forceinline__ void gload16(const void* g, void* l) {
    __builtin_amdgcn_global_load_lds(
        (const __attribute__((address_space(1))) void*)g,
        (__attribute__((address_space(3))) void*)l, 16, 0, 0);
}

__device__ __forceinline__ f32x4 exp4(f32x4 v) {
    f32x4 r;
    r.x = __expf(v.x); r.y = __expf(v.y); r.z = __expf(v.z); r.w = __expf(v.w);
    return r;
}

// f32 -> fp8 e4m3fn (OCP), RNE, with subnormal support. |f| < 448 assumed.
__device__ __forceinline__ unsigned f2e4m3(float f) {
    union { float f; unsigned u; } v; v.f = f;
    unsigned s = (v.u >> 24) & 0x80u;
    unsigned mag = v.u & 0x7fffffffu;
    int e = (int)(mag >> 23) - 127;
    if (e >= -6) {  // normal range for e4m3
        unsigned r = mag + 0x7ffffu + ((mag >> 20) & 1u);   // RNE into 3 mantissa bits
        int e2 = (int)(r >> 23) - 127;
        unsigned m3 = (r >> 20) & 7u;
        return s | (unsigned)((e2 + 7) << 3) | m3;
    }
    if (e < -10) return s;                                   // underflow to 0
    float q = rintf(fabsf(f) * 512.0f);                      // subnormal: units of 2^-9
    unsigned qi = (unsigned)q;                               // 0..8
    return s | qi;                                           // qi==8 -> 0x08 == 2^-6 normal
}

// ------------- Kernel A: normalize pair rows -> fp8 zn (grouped layout) + pos dot -------------
// zn row layout (256 B): 4 K-groups of 64 B; group g, 16B unit y in [0,4):
//   bytes [g*64 + y*16 .. +8)  = k in [g*64 + y*8,      +8)   (K-half 0)
//   bytes [g*64 + y*16 + 8 ..) = k in [g*64 + 32 + y*8, +8)   (K-half 1)
// lane l covers k = l*4..l*4+4 -> one u32 at byte g*64 + c*16 + h*8 + 4*(l&1),
//   g = l>>4, c = (l>>1)&3, h = (l>>3)&1.
__global__ __launch_bounds__(256) void normpos_kernel(const float* __restrict__ zi,
                                                      const float* __restrict__ zj,
                                                      unsigned char* __restrict__ zn,
                                                      float* __restrict__ pospartial) {
    int wid = threadIdx.x >> 6;
    int lane = threadIdx.x & 63;
    int p = blockIdx.x * 4 + wid;          // 0..B_ROWS-1
    f32x4 ga = *(const f32x4*)(zi + (size_t)p * D_DIM + lane * 4);
    f32x4 gb = *(const f32x4*)(zj + (size_t)p * D_DIM + lane * 4);
    float sa = ga.x * ga.x + ga.y * ga.y + ga.z * ga.z + ga.w * ga.w;
    float sb = gb.x * gb.x + gb.y * gb.y + gb.z * gb.z + gb.w * gb.w;
    #pragma unroll
    for (int m = 1; m < 64; m <<= 1) { sa += __shfl_xor(sa, m, 64); sb += __shfl_xor(sb, m, 64); }
    float fa = 1.41421356237309515f / fmaxf(sqrtf(sa), 1e-8f);
    float fb = 1.41421356237309515f / fmaxf(sqrtf(sb), 1e-8f);
    f32x4 na, nb;
    na.x = ga.x * fa; na.y = ga.y * fa; na.z = ga.z * fa; na.w = ga.w * fa;
    nb.x = gb.x * fb; nb.y = gb.y * fb; nb.z = gb.z * fb; nb.w = gb.w * fb;
    unsigned pa = f2e4m3(na.x) | (f2e4m3(na.y) << 8) | (f2e4m3(na.z) << 16) | (f2e4m3(na.w) << 24);
    unsigned pb = f2e4m3(nb.x) | (f2e4m3(nb.y) << 8) | (f2e4m3(nb.z) << 16) | (f2e4m3(nb.w) << 24);
    int bytepos = (lane >> 4) * 64 + ((lane >> 1) & 3) * 16 + ((lane >> 3) & 1) * 8 + 4 * (lane & 1);
    *(unsigned*)(zn + (size_t)p * 256 + bytepos) = pa;
    *(unsigned*)(zn + (size_t)(p + B_ROWS) * 256 + bytepos) = pb;
    // pos dot in f32 (reference-accurate)
    float d = na.x * nb.x + na.y * nb.y + na.z * nb.z + na.w * nb.w;
    #pragma unroll
    for (int m = 1; m < 64; m <<= 1) d += __shfl_xor(d, m, 64);
    if (lane == 0) pospartial[p] = d;
}

// ------------- Kernel C: fp8 128x128 GEMM, WHOLE K staged, ONE barrier -------------
// 4 waves (2x2), wave-tile 64x64 (acc 4x4). Stage A(32KB)+B(32KB) for all K=256,
// one __syncthreads, then unbroken 32 ds_read_b128 + 128 MFMA stream per wave
// (compiler-pipelined lgkmcnt). Swizzle: 16B slot y at y ^ ((row>>1)&3) per 64B group.
__global__ __launch_bounds__(256, 2) void simclr_gemm_kernel(const unsigned char* __restrict__ zn,
                                                             float* __restrict__ P) {
    __shared__ unsigned char As[4 * 8192];   // 32 KB: [g][row][slot]
    __shared__ unsigned char Bs[4 * 8192];   // 32 KB
    __shared__ float rPpart[2][BT];
    __shared__ float cPpart[2][BT];

    const int tid = threadIdx.x;
    const int lane = tid & 63, wid = tid >> 6;
    const int wr = wid >> 1, wc = wid & 1;      // 2x2 wave grid

    // XCD-bijective chunked swizzle (2080 % 8 == 0)
    int bid = (int)((blockIdx.x & 7) * (NTILES / 8) + (blockIdx.x >> 3));
    // decode bid -> (ti,tj), ti<=tj, row-major upper triangle (TGRID=64)
    int ti = (int)((129.0f - sqrtf(16641.0f - 8.0f * (float)bid)) * 0.5f);
    while ((ti + 1) * TGRID - ((ti + 1) * ti) / 2 <= bid) ++ti;
    while (ti * TGRID - (ti * (ti - 1)) / 2 > bid) --ti;
    const int tj = ti + (bid - (ti * TGRID - (ti * (ti - 1)) / 2));

    const char* gA = (const char*)zn + (size_t)ti * BT * 256;   // row stride 256 B
    const char* gB = (const char*)zn + (size_t)tj * BT * 256;

    // staging: 8 issues per matrix; issue (g, h): rows h*64 + (tid>>2), K-group g,
    // 16B slot tid&3, source pre-swizzled sch = (tid&3) ^ ((tid>>3)&3) = slot^((row>>1)&3).
    // LDS: As[g*8192 + h*4096 + tid*16] (linear per issue).
    const int r0 = tid >> 2;
    const int sch = (tid & 3) ^ ((tid >> 3) & 3);
    const unsigned lo = (unsigned)tid * 16;

    #pragma unroll
    for (int g = 0; g < 4; ++g) {
        #pragma unroll
        for (int h = 0; h < 2; ++h) {
            size_t go = (size_t)(h * 64 + r0) * 256 + (size_t)g * 64 + (size_t)sch * 16;
            gload16(gA + go, &As[g * 8192 + h * 4096 + lo]);
            gload16(gB + go, &Bs[g * 8192 + h * 4096 + lo]);
        }
    }

    f32x4 acc[4][4];
    #pragma unroll
    for (int m = 0; m < 4; ++m)
        #pragma unroll
        for (int n = 0; n < 4; ++n)
            acc[m][n] = (f32x4){0.f, 0.f, 0.f, 0.f};

    // frag read: row r, 16B unit y=(lane>>4) at byte g*8192 + r*64 + (y ^ ((r>>1)&3))*16;
    // frag row bases x16 so (r>>1)&3 = ((lane&15)>>1)&3.
    const int ysw = (lane >> 4) ^ (((lane & 15) >> 1) & 3);
    const int arow = wr * 64 + (lane & 15);
    const int brow = wc * 64 + (lane & 15);

    __syncthreads();                 // the ONLY pre-epilogue barrier: all staging visible

    #pragma unroll
    for (int g = 0; g < 4; ++g) {
        u64x2 af[4], bfr[4];
        #pragma unroll
        for (int m = 0; m < 4; ++m)
            af[m] = *(const u64x2*)&As[g * 8192 + (arow + m * 16) * 64 + ysw * 16];
        #pragma unroll
        for (int n = 0; n < 4; ++n)
            bfr[n] = *(const u64x2*)&Bs[g * 8192 + (brow + n * 16) * 64 + ysw * 16];
        #pragma unroll
        for (int m = 0; m < 4; ++m)
            #pragma unroll
            for (int n = 0; n < 4; ++n) {
                acc[m][n] = __builtin_amdgcn_mfma_f32_16x16x32_fp8_fp8(
                    (long)af[m].x, (long)bfr[n].x, acc[m][n], 0, 0, 0);
                acc[m][n] = __builtin_amdgcn_mfma_f32_16x16x32_fp8_fp8(
                    (long)af[m].y, (long)bfr[n].y, acc[m][n], 0, 0, 0);
            }
    }

    // ---- epilogue: exp; unique-writer LDS partials (no atomics) ----
    float cs[4] = {0.f, 0.f, 0.f, 0.f};
    #pragma unroll
    for (int m = 0; m < 4; ++m) {
        f32x4 ef[4];
        #pragma unroll
        for (int n = 0; n < 4; ++n) ef[n] = exp4(acc[m][n]);
        f32x4 rv = ef[0] + ef[1] + ef[2] + ef[3];
        #pragma unroll
        for (int msk = 1; msk <= 8; msk <<= 1) {
            rv.x += __shfl_xor(rv.x, msk, 64);
            rv.y += __shfl_xor(rv.y, msk, 64);
            rv.z += __shfl_xor(rv.z, msk, 64);
            rv.w += __shfl_xor(rv.w, msk, 64);
        }
        if ((lane & 15) == 0) {
            int rbase = wr * 64 + m * 16 + (lane >> 4) * 4;
            rPpart[wc][rbase + 0] = rv.x;
            rPpart[wc][rbase + 1] = rv.y;
            rPpart[wc][rbase + 2] = rv.z;
            rPpart[wc][rbase + 3] = rv.w;
        }
        #pragma unroll
        for (int n = 0; n < 4; ++n)
            cs[n] += ef[n].x + ef[n].y + ef[n].z + ef[n].w;
    }
    #pragma unroll
    for (int n = 0; n < 4; ++n) {
        float c = cs[n];
        c += __shfl_xor(c, 16, 64);
        c += __shfl_xor(c, 32, 64);
        if (lane < 16) cPpart[wr][wc * 64 + n * 16 + lane] = c;
    }
    __syncthreads();

    if (tid < BT) {
        P[(size_t)tj * N_ROWS + ti * BT + tid] = rPpart[0][tid] + rPpart[1][tid];
    } else if (ti != tj) {
        int t = tid - BT;
        P[(size_t)ti * N_ROWS + tj * BT + t] = cPpart[0][t] + cPpart[1][t];
    }
}

// ------------- Kernel E: per-row reduce over 64 slots + log (+fold pos) -------------
__global__ __launch_bounds__(256) void reduce_rows_kernel(const float* __restrict__ P,
                                                          const float* __restrict__ pospartial,
                                                          float* __restrict__ blockpart) {
    const float E2 = 7.38905609893065f;   // exp(self-sim) = e^2
    int row = blockIdx.x * 256 + threadIdx.x;
    float s = 0.f;
    #pragma unroll 16
    for (int src = 0; src < TGRID; ++src)
        s += P[(size_t)src * N_ROWS + row];
    float v = logf(s - E2);
    if (threadIdx.x < 128)
        v -= 2.0f * pospartial[blockIdx.x * 128 + threadIdx.x];
    #pragma unroll
    for (int m = 1; m < 64; m <<= 1) v += __shfl_xor(v, m, 64);
    __shared__ float ws[4];
    if ((threadIdx.x & 63) == 0) ws[threadIdx.x >> 6] = v;
    __syncthreads();
    if (threadIdx.x == 0) blockpart[blockIdx.x] = ws[0] + ws[1] + ws[2] + ws[3];
}

// ------------- Kernel F: out = sum(blockpart) / N -------------
__global__ __launch_bounds__(64) void final_kernel(const float* __restrict__ blockpart,
                                                   float* __restrict__ out) {
    int lane = threadIdx.x;
    float v = (lane < 32) ? blockpart[lane] : 0.f;
    #pragma unroll
    for (int m = 1; m < 64; m <<= 1) v += __shfl_xor(v, m, 64);
    if (lane == 0) out[0] = v / (float)N_ROWS;
}

extern "C" void kernel_launch(void* const* d_in, const int* in_sizes, int n_in,
                              void* d_out, int out_size, void* d_ws, size_t ws_size,
                              hipStream_t stream) {
    const float* zi = (const float*)d_in[0];
    const float* zj = (const float*)d_in[1];
    char* ws = (char*)d_ws;
    unsigned char* zn = (unsigned char*)ws;                          // 2 MB (8192 x 256 B)
    float* P = (float*)(ws + 2 * 1024 * 1024);                       // 2 MB (64 x 8192 f32)
    float* pospartial = (float*)(ws + 4 * 1024 * 1024);              // 16 KB
    float* blockpart = (float*)(ws + 4 * 1024 * 1024 + 16 * 1024);   // 128 B

    normpos_kernel<<<B_ROWS / 4, 256, 0, stream>>>(zi, zj, zn, pospartial);
    simclr_gemm_kernel<<<NTILES, 256, 0, stream>>>(zn, P);
    reduce_rows_kernel<<<N_ROWS / 256, 256, 0, stream>>>(P, pospartial, blockpart);
    final_kernel<<<1, 64, 0, stream>>>(blockpart, (float*)d_out);
}